// Round 20
// baseline (211.949 us; speedup 1.0000x reference)
//
#include <hip/hip_runtime.h>

typedef __attribute__((ext_vector_type(8))) short bf16x8;
typedef __attribute__((ext_vector_type(4))) float f32x4;

#define MFMA16(A,B,C) __builtin_amdgcn_mfma_f32_16x16x32_bf16(A,B,C,0,0,0)

typedef const __attribute__((address_space(1))) void gas_t;
typedef __attribute__((address_space(3))) void las_t;
#define GLOAD16(g, l) __builtin_amdgcn_global_load_lds((gas_t*)(g), (las_t*)(l), 16, 0, 0)

__device__ __forceinline__ unsigned short f2bf(float f){
  unsigned int u = __float_as_uint(f);
  u += 0x7FFFu + ((u >> 16) & 1u);        // round-to-nearest-even
  return (unsigned short)(u >> 16);
}
__device__ __forceinline__ float bf2f(unsigned short s){
  return __uint_as_float(((unsigned int)s) << 16);
}
// byte offset into a [rows][64] bf16 LDS tile (128B rows), XOR-swizzled (G4)
__device__ __forceinline__ int swz(int row, int kbyte){
  return (row * 128 + kbyte) ^ ((row & 7) << 4);
}

// -- prep: weight transposes (LDS-tiled) + hop->byte transpose + x->bf16 ----
// blocks 0-255: wqT/woT 64x64 f32 tiles; 256-511: hop8T[w][v] uchar tiles;
// 512-1535: xb convert.
__global__ __launch_bounds__(256) void k_prep(
    const float* __restrict__ w_qkv, const float* __restrict__ w_out,
    const float* __restrict__ x, const int* __restrict__ hop,
    unsigned short* __restrict__ wqT, unsigned short* __restrict__ woT,
    unsigned short* __restrict__ xb, unsigned char* __restrict__ hop8T)
{
  __shared__ float tile[64][65];
  __shared__ int itile[64][65];
  const int bid = blockIdx.x, tid = threadIdx.x;
  const int c = tid & 63, r4 = tid >> 6;
  if (bid < 256) {
    // weight transpose: coalesced reads along n, coalesced writes along kq
    const float* src; unsigned short* dst; int srcld, kq0, n0;
    if (bid < 192) {                       // wqT: 24 n-tiles x 8 kq-tiles
      int tn = bid >> 3, tk = bid & 7;
      src = w_qkv; dst = wqT; srcld = 1536; kq0 = tk * 64; n0 = tn * 64;
    } else {                               // woT: 8 x 8 tiles
      int j = bid - 192; int tn = j >> 3, tk = j & 7;
      src = w_out; dst = woT; srcld = 512; kq0 = tk * 64; n0 = tn * 64;
    }
#pragma unroll
    for (int i = 0; i < 16; ++i) {
      int rr = r4 * 16 + i;
      tile[rr][c] = src[(size_t)(kq0 + rr) * srcld + n0 + c];
    }
    __syncthreads();
#pragma unroll
    for (int i = 0; i < 16; ++i) {
      int rr = r4 * 16 + i;                // output row = n index
      dst[(size_t)(n0 + rr) * 512 + kq0 + c] = f2bf(tile[c][rr]);
    }
  } else if (bid < 512) {                  // hop8T: 16x16 grid of 64x64 tiles
    int j = bid - 256; int tv = j >> 4, tw = j & 15;
#pragma unroll
    for (int i = 0; i < 16; ++i) {
      int rr = r4 * 16 + i;
      itile[rr][c] = hop[(size_t)(tv * 64 + rr) * 1024 + tw * 64 + c];
    }
    __syncthreads();
#pragma unroll
    for (int i = 0; i < 16; ++i) {
      int rr = r4 * 16 + i;                // output row = w index
      hop8T[(size_t)(tw * 64 + rr) * 1024 + tv * 64 + c] =
          (unsigned char)itile[c][rr];
    }
  } else {                                 // xb: 1024 blocks x 1024 quads
    int base = (bid - 512) * 1024 + tid;
#pragma unroll
    for (int i = 0; i < 4; ++i) {
      int j = base + i * 256;
      float4 xv = *reinterpret_cast<const float4*>(x + (size_t)j * 4);
      ushort4 o;
      o.x = f2bf(xv.x); o.y = f2bf(xv.y); o.z = f2bf(xv.z); o.w = f2bf(xv.w);
      *reinterpret_cast<ushort4*>(xb + (size_t)j * 4) = o;
    }
  }
}

// ------- QKV GEMM: qkv = xb @ w_qkv, async global_load_lds staging ---------
__global__ __launch_bounds__(256) void k_qkv(
    const unsigned short* __restrict__ xb, const unsigned short* __restrict__ wqT,
    unsigned short* __restrict__ q, unsigned short* __restrict__ k_,
    unsigned short* __restrict__ valT)
{
  __shared__ char lds[32768];
  char* At = lds; char* Bt = lds + 16384;
  const int tid = threadIdx.x;
  const int wid = tid >> 6, lane = tid & 63, g = lane >> 4, r = lane & 15;
  const int wm = wid >> 1, wn = wid & 1;
  const int m0 = blockIdx.x * 128, n0 = blockIdx.y * 128;
  const int l8 = lane >> 3;
  const int colel = ((lane & 7) ^ l8) * 8;   // pre-swizzled source column (elems)

  f32x4 acc[4][4];
#pragma unroll
  for (int a = 0; a < 4; ++a)
#pragma unroll
    for (int b = 0; b < 4; ++b) acc[a][b] = (f32x4){0.f, 0.f, 0.f, 0.f};

  for (int kt = 0; kt < 8; ++kt) {
    const int k0 = kt * 64;
    __syncthreads();
#pragma unroll
    for (int i = 0; i < 4; ++i) {
      int row = wid * 32 + i * 8 + l8;
      GLOAD16(xb  + (size_t)(m0 + row) * 512 + k0 + colel, At + wid * 4096 + i * 1024);
      GLOAD16(wqT + (size_t)(n0 + row) * 512 + k0 + colel, Bt + wid * 4096 + i * 1024);
    }
    __syncthreads();
#pragma unroll
    for (int kk = 0; kk < 2; ++kk) {
      bf16x8 af[4], bf[4];
      const int kb = (kk * 32 + 8 * g) * 2;
#pragma unroll
      for (int mi = 0; mi < 4; ++mi)
        af[mi] = *reinterpret_cast<const bf16x8*>(At + swz(wm * 64 + mi * 16 + r, kb));
#pragma unroll
      for (int ni = 0; ni < 4; ++ni)
        bf[ni] = *reinterpret_cast<const bf16x8*>(Bt + swz(wn * 64 + ni * 16 + r, kb));
#pragma unroll
      for (int mi = 0; mi < 4; ++mi)
#pragma unroll
        for (int ni = 0; ni < 4; ++ni)
          acc[mi][ni] = MFMA16(af[mi], bf[ni], acc[mi][ni]);
    }
  }
  const int s = n0 >> 9;  // 0=q 1=k 2=val
#pragma unroll
  for (int mi = 0; mi < 4; ++mi)
#pragma unroll
    for (int ni = 0; ni < 4; ++ni)
#pragma unroll
      for (int i = 0; i < 4; ++i) {
        int m = m0 + wm * 64 + mi * 16 + 4 * g + i;   // D row = 4g+i (m89)
        int n = n0 + wn * 64 + ni * 16 + r;           // D col = lane&15
        int b = m >> 10, v = m & 1023;
        int cc = n & 511, h = cc >> 6, d = cc & 63;
        int bh = b * 8 + h;
        unsigned short bfv = f2bf(acc[mi][ni][i]);
        if (s == 2)      valT[((size_t)bh * 64 + d) * 1024 + v] = bfv;
        else if (s == 0) q [((size_t)bh * 1024 + v) * 64 + d] = bfv;
        else             k_[((size_t)bh * 1024 + v) * 64 + d] = bfv;
      }
}

// ------- attention: on-the-fly bias gather (hop8T bytes + 9-float LDS) -----
// One block = (b,h, 16 q-rows). Wave w owns score cols [256w, 256w+256).
// No bias staging: per ct one aligned u32 of hop codes + rl[] LDS broadcast.
#define PSTR 1032
__global__ __launch_bounds__(256, 4) void k_attn(
    const unsigned short* __restrict__ q, const unsigned short* __restrict__ k_,
    const unsigned short* __restrict__ valT,
    const unsigned char* __restrict__ hop8T,
    const float* __restrict__ rpe_bias,
    float* __restrict__ attn, unsigned short* __restrict__ oh)
{
  __shared__ unsigned short P[16 * PSTR];   // bf16, 33 KB (P only)
  __shared__ float red[2][4][16];
  __shared__ float rl[9];
  const int tid = threadIdx.x;
  const int wid = tid >> 6, lane = tid & 63, g = lane >> 4, r = lane & 15;
  // bijective XCD swizzle (4096 % 8 == 0): XCD j gets work ids [512j, 512j+512)
  const int blk = ((blockIdx.x & 7) << 9) | (blockIdx.x >> 3);
  const int h  = blk >> 9;                  // outermost: one head per XCD
  const int vt = (blk >> 3) & 63;
  const int b  = blk & 7;                   // innermost: hop-row sharers adjacent
  const int bh = b * 8 + h;
  const int v0 = vt * 16;

  if (tid < 9) rl[tid] = rpe_bias[h * 9 + tid];

  // Q fragments in registers (A-operand: row=r, k-slice 8g)
  const unsigned short* qp = q + ((size_t)bh * 1024 + v0) * 64;
  bf16x8 qf[2];
#pragma unroll
  for (int kk = 0; kk < 2; ++kk)
    qf[kk] = *reinterpret_cast<const bf16x8*>(qp + r * 64 + kk * 32 + 8 * g);
  __syncthreads();                          // rl visible

  // QK: scores in registers; bias via hop-code u32 + LDS table
  const unsigned short* kb = k_ + (size_t)bh * 65536;
  f32x4 s[16];
#pragma unroll
  for (int ct = 0; ct < 16; ++ct) {
    const int wcol = wid * 256 + ct * 16 + r;
    unsigned int hv = *reinterpret_cast<const unsigned int*>(
        hop8T + (size_t)wcol * 1024 + v0 + 4 * g);   // rows 4g..4g+3, aligned
    f32x4 acc = (f32x4){0.f, 0.f, 0.f, 0.f};
#pragma unroll
    for (int kk = 0; kk < 2; ++kk) {
      bf16x8 kf = *reinterpret_cast<const bf16x8*>(kb + (size_t)wcol * 64 + kk * 32 + 8 * g);
      acc = MFMA16(qf[kk], kf, acc);
    }
#pragma unroll
    for (int i = 0; i < 4; ++i)
      s[ct][i] = (acc[i] + rl[(hv >> (8 * i)) & 0xFF]) * 0.125f;
  }

  // per-row max: local over ct, then shfl over the 16-lane r-group
  float mx[4] = {-1e30f, -1e30f, -1e30f, -1e30f};
#pragma unroll
  for (int ct = 0; ct < 16; ++ct)
#pragma unroll
    for (int i = 0; i < 4; ++i) mx[i] = fmaxf(mx[i], s[ct][i]);
#pragma unroll
  for (int o = 1; o <= 8; o <<= 1)
#pragma unroll
    for (int i = 0; i < 4; ++i) mx[i] = fmaxf(mx[i], __shfl_xor(mx[i], o, 64));
  if (r == 0)
#pragma unroll
    for (int i = 0; i < 4; ++i) red[0][wid][4 * g + i] = mx[i];
  __syncthreads();
#pragma unroll
  for (int i = 0; i < 4; ++i) {
    float M = red[0][0][4 * g + i];
#pragma unroll
    for (int w = 1; w < 4; ++w) M = fmaxf(M, red[0][w][4 * g + i]);
    mx[i] = M;
  }

  // exp + per-row sum
  float sm[4] = {0.f, 0.f, 0.f, 0.f};
#pragma unroll
  for (int ct = 0; ct < 16; ++ct)
#pragma unroll
    for (int i = 0; i < 4; ++i) {
      float e = __expf(s[ct][i] - mx[i]);
      s[ct][i] = e;
      sm[i] += e;
    }
#pragma unroll
  for (int o = 1; o <= 8; o <<= 1)
#pragma unroll
    for (int i = 0; i < 4; ++i) sm[i] += __shfl_xor(sm[i], o, 64);
  if (r == 0)
#pragma unroll
    for (int i = 0; i < 4; ++i) red[1][wid][4 * g + i] = sm[i];
  __syncthreads();
  float inv[4];
#pragma unroll
  for (int i = 0; i < 4; ++i) {
    float T = red[1][0][4 * g + i] + red[1][1][4 * g + i] +
              red[1][2][4 * g + i] + red[1][3][4 * g + i];
    inv[i] = 1.0f / T;
  }

  // normalize into bf16 P (P has no other use now — no ordering constraint)
#pragma unroll
  for (int ct = 0; ct < 16; ++ct) {
    const int col = wid * 256 + ct * 16 + r;
#pragma unroll
    for (int i = 0; i < 4; ++i)
      P[(4 * g + i) * PSTR + col] = f2bf(s[ct][i] * inv[i]);
  }
  __syncthreads();

  // coalesced attn write from P: lane -> f32x4 (16B) nontemporal, 1KB/wave.
  float* ab = attn + ((size_t)bh * 1024 + v0) * 1024;
#pragma unroll
  for (int it = 0; it < 16; ++it) {
    int e = tid + it * 256;                 // 0..4095: row=e>>8, quad=e&255
    int row = e >> 8, q4 = e & 255;
    uint2 pv = *reinterpret_cast<const uint2*>(&P[row * PSTR + q4 * 4]);
    f32x4 o;
    o[0] = bf2f((unsigned short)(pv.x      ));
    o[1] = bf2f((unsigned short)(pv.x >> 16));
    o[2] = bf2f((unsigned short)(pv.y      ));
    o[3] = bf2f((unsigned short)(pv.y >> 16));
    __builtin_nontemporal_store(o, reinterpret_cast<f32x4*>(ab + (size_t)row * 1024 + q4 * 4));
  }

  // PV: out(16x64) = P(16x1024) @ val(1024x64); wave owns 16 out cols.
  const unsigned short* vT = valT + ((size_t)bh * 64 + wid * 16) * 1024;
  f32x4 a0 = (f32x4){0.f,0.f,0.f,0.f}, a1 = a0;
  for (int kc = 0; kc < 32; kc += 2) {
    const int base = r * PSTR, vbase = kc * 32 + 8 * g;
    bf16x8 p0 = *reinterpret_cast<const bf16x8*>(&P[base + vbase]);
    bf16x8 p1 = *reinterpret_cast<const bf16x8*>(&P[base + vbase + 32]);
    bf16x8 v0_ = *reinterpret_cast<const bf16x8*>(vT + (size_t)r * 1024 + vbase);
    bf16x8 v1_ = *reinterpret_cast<const bf16x8*>(vT + (size_t)r * 1024 + vbase + 32);
    a0 = MFMA16(p0, v0_, a0);
    a1 = MFMA16(p1, v1_, a1);
  }
  f32x4 acc = a0 + a1;
#pragma unroll
  for (int i = 0; i < 4; ++i) {
    size_t oi = ((size_t)(b * 1024 + v0 + 4 * g + i)) * 512 + h * 64 + wid * 16 + r;
    oh[oi] = f2bf(acc[i]);
  }
}

// ------- output GEMM: out = oh @ w_out + b_out, async staging --------------
__global__ __launch_bounds__(256) void k_out(
    const unsigned short* __restrict__ oh, const unsigned short* __restrict__ woT,
    const float* __restrict__ b_out, float* __restrict__ out)
{
  __shared__ char lds[32768];
  char* At = lds; char* Bt = lds + 16384;
  const int tid = threadIdx.x;
  const int wid = tid >> 6, lane = tid & 63, g = lane >> 4, r = lane & 15;
  const int wm = wid >> 1, wn = wid & 1;
  const int m0 = blockIdx.x * 128, n0 = blockIdx.y * 128;
  const int l8 = lane >> 3;
  const int colel = ((lane & 7) ^ l8) * 8;   // pre-swizzled source column (elems)

  f32x4 acc[4][4];
#pragma unroll
  for (int a = 0; a < 4; ++a)
#pragma unroll
    for (int b = 0; b < 4; ++b) acc[a][b] = (f32x4){0.f, 0.f, 0.f, 0.f};

  for (int kt = 0; kt < 8; ++kt) {
    const int k0 = kt * 64;
    __syncthreads();
#pragma unroll
    for (int i = 0; i < 4; ++i) {
      int row = wid * 32 + i * 8 + l8;
      GLOAD16(oh  + (size_t)(m0 + row) * 512 + k0 + colel, At + wid * 4096 + i * 1024);
      GLOAD16(woT + (size_t)(n0 + row) * 512 + k0 + colel, Bt + wid * 4096 + i * 1024);
    }
    __syncthreads();
#pragma unroll
    for (int kk = 0; kk < 2; ++kk) {
      bf16x8 a4[4], b4[4];
      const int kb = (kk * 32 + 8 * g) * 2;
#pragma unroll
      for (int mi = 0; mi < 4; ++mi)
        a4[mi] = *reinterpret_cast<const bf16x8*>(At + swz(wm * 64 + mi * 16 + r, kb));
#pragma unroll
      for (int ni = 0; ni < 4; ++ni)
        b4[ni] = *reinterpret_cast<const bf16x8*>(Bt + swz(wn * 64 + ni * 16 + r, kb));
#pragma unroll
      for (int mi = 0; mi < 4; ++mi)
#pragma unroll
        for (int ni = 0; ni < 4; ++ni)
          acc[mi][ni] = MFMA16(a4[mi], b4[ni], acc[mi][ni]);
    }
  }
#pragma unroll
  for (int mi = 0; mi < 4; ++mi)
#pragma unroll
    for (int ni = 0; ni < 4; ++ni)
#pragma unroll
      for (int i = 0; i < 4; ++i) {
        int m = m0 + wm * 64 + mi * 16 + 4 * g + i;
        int n = n0 + wn * 64 + ni * 16 + r;
        float v = acc[mi][ni][i] + b_out[n];
        __builtin_nontemporal_store(v, out + (size_t)m * 512 + n);
      }
}

extern "C" void kernel_launch(void* const* d_in, const int* in_sizes, int n_in,
                              void* d_out, int out_size, void* d_ws, size_t ws_size,
                              hipStream_t stream) {
  // Bind inputs BY SIZE (all six element counts distinct) — immune to order.
  const float *x = nullptr, *w_qkv = nullptr, *w_out = nullptr,
              *b_out = nullptr, *rpe = nullptr;
  const int* hop = nullptr;
  for (int i = 0; i < n_in; ++i) {
    switch (in_sizes[i]) {
      case 4194304: x     = (const float*)d_in[i]; break;  // (8,1024,512)
      case 786432:  w_qkv = (const float*)d_in[i]; break;  // (512,1536)
      case 262144:  w_out = (const float*)d_in[i]; break;  // (512,512)
      case 512:     b_out = (const float*)d_in[i]; break;  // (512,)
      case 72:      rpe   = (const float*)d_in[i]; break;  // (8,9)
      case 1048576: hop   = (const int*)d_in[i];   break;  // (1024,1024) int32
    }
  }

  float* out  = (float*)d_out;                 // f32 outputs
  float* attn = out + (size_t)4194304;         // attn section (8,8,1024,1024)

  char* ws = (char*)d_ws;
  unsigned short* q_    = (unsigned short*)(ws);                   // 8 MB
  unsigned short* k_    = (unsigned short*)(ws + (size_t) 8388608);// 8 MB
  unsigned short* valT  = (unsigned short*)(ws + (size_t)16777216);// 8 MB
  unsigned short* oh    = (unsigned short*)(ws + (size_t)25165824);// 8 MB
  unsigned short* wqT   = (unsigned short*)(ws + (size_t)33554432);// 1.5 MB
  unsigned short* woT   = (unsigned short*)(ws + (size_t)35127296);// 0.5 MB
  unsigned char*  hop8T = (unsigned char*)(ws + (size_t)35651584); // 1 MB
  unsigned short* xb    = (unsigned short*)(ws + (size_t)52428800);// 8 MB
  // total ~60 MB of d_ws

  // prep grid: 256 weight-transpose + 256 hop-transpose + 1024 xb blocks
  k_prep<<<dim3(1536), dim3(256), 0, stream>>>(w_qkv, w_out, x, hop,
                                               wqT, woT, xb, hop8T);
  k_qkv<<<dim3(64, 12), dim3(256), 0, stream>>>(xb, wqT, q_, k_, valT);
  k_attn<<<dim3(4096), dim3(256), 0, stream>>>(q_, k_, valT, hop8T, rpe, attn, oh);
  k_out<<<dim3(64, 4), dim3(256), 0, stream>>>(oh, woT, b_out, out);
}

// Round 21
// 208.774 us; speedup vs baseline: 1.0152x; 1.0152x over previous
//
#include <hip/hip_runtime.h>

typedef __attribute__((ext_vector_type(8))) short bf16x8;
typedef __attribute__((ext_vector_type(4))) float f32x4;

#define MFMA16(A,B,C) __builtin_amdgcn_mfma_f32_16x16x32_bf16(A,B,C,0,0,0)

typedef const __attribute__((address_space(1))) void gas_t;
typedef __attribute__((address_space(3))) void las_t;
#define GLOAD16(g, l) __builtin_amdgcn_global_load_lds((gas_t*)(g), (las_t*)(l), 16, 0, 0)

__device__ __forceinline__ unsigned short f2bf(float f){
  unsigned int u = __float_as_uint(f);
  u += 0x7FFFu + ((u >> 16) & 1u);        // round-to-nearest-even
  return (unsigned short)(u >> 16);
}
__device__ __forceinline__ float bf2f(unsigned short s){
  return __uint_as_float(((unsigned int)s) << 16);
}
// byte offset into a [rows][64] bf16 LDS tile (128B rows), XOR-swizzled (G4)
__device__ __forceinline__ int swz(int row, int kbyte){
  return (row * 128 + kbyte) ^ ((row & 7) << 4);
}

// -- prep (merged, tiled-transpose): blocks 0-255 transpose wqT/woT via LDS
//    (64x64 f32 tile, [64][65] padding); 256-1279 xb convert; 1280+ bias.
__global__ __launch_bounds__(256) void k_prep(
    const float* __restrict__ w_qkv, const float* __restrict__ w_out,
    const float* __restrict__ x,
    const int* __restrict__ hop, const float* __restrict__ rpe_bias,
    unsigned short* __restrict__ wqT, unsigned short* __restrict__ woT,
    unsigned short* __restrict__ xb, unsigned short* __restrict__ biasT)
{
  __shared__ float tile[64][65];
  __shared__ float rl[72];
  const int bid = blockIdx.x, tid = threadIdx.x;
  if (bid < 256) {
    // tiled transpose: coalesced reads along n, coalesced writes along kq
    const float* src; unsigned short* dst; int srcld, kq0, n0;
    if (bid < 192) {                       // wqT: 24 n-tiles x 8 kq-tiles
      int tn = bid >> 3, tk = bid & 7;
      src = w_qkv; dst = wqT; srcld = 1536; kq0 = tk * 64; n0 = tn * 64;
    } else {                               // woT: 8 x 8 tiles
      int j = bid - 192; int tn = j >> 3, tk = j & 7;
      src = w_out; dst = woT; srcld = 512; kq0 = tk * 64; n0 = tn * 64;
    }
    const int c = tid & 63, r4 = tid >> 6;
#pragma unroll
    for (int i = 0; i < 16; ++i) {
      int rr = r4 * 16 + i;
      tile[rr][c] = src[(size_t)(kq0 + rr) * srcld + n0 + c];
    }
    __syncthreads();
#pragma unroll
    for (int i = 0; i < 16; ++i) {
      int rr = r4 * 16 + i;                // output row = n index
      dst[(size_t)(n0 + rr) * 512 + kq0 + c] = f2bf(tile[c][rr]);
    }
  } else if (bid < 1280) {                 // xb: 1024 blocks x 1024 quads
    int base = (bid - 256) * 1024 + tid;
#pragma unroll
    for (int i = 0; i < 4; ++i) {
      int j = base + i * 256;
      float4 xv = *reinterpret_cast<const float4*>(x + (size_t)j * 4);
      ushort4 o;
      o.x = f2bf(xv.x); o.y = f2bf(xv.y); o.z = f2bf(xv.z); o.w = f2bf(xv.w);
      *reinterpret_cast<ushort4*>(xb + (size_t)j * 4) = o;
    }
  } else {                                 // bias: 4096 blocks, coalesced
    if (tid < 72) rl[tid] = rpe_bias[tid];
    __syncthreads();
    int j = (bid - 1280) * 256 + tid;
    int hv = hop[j];
#pragma unroll
    for (int h = 0; h < 8; ++h)
      biasT[((size_t)h << 20) + j] = f2bf(rl[h * 9 + hv]);
  }
}

// ------- QKV GEMM: qkv = xb @ w_qkv, async global_load_lds staging ---------
__global__ __launch_bounds__(256) void k_qkv(
    const unsigned short* __restrict__ xb, const unsigned short* __restrict__ wqT,
    unsigned short* __restrict__ q, unsigned short* __restrict__ k_,
    unsigned short* __restrict__ valT)
{
  __shared__ char lds[32768];
  char* At = lds; char* Bt = lds + 16384;
  const int tid = threadIdx.x;
  const int wid = tid >> 6, lane = tid & 63, g = lane >> 4, r = lane & 15;
  const int wm = wid >> 1, wn = wid & 1;
  const int m0 = blockIdx.x * 128, n0 = blockIdx.y * 128;
  const int l8 = lane >> 3;
  const int colel = ((lane & 7) ^ l8) * 8;   // pre-swizzled source column (elems)

  f32x4 acc[4][4];
#pragma unroll
  for (int a = 0; a < 4; ++a)
#pragma unroll
    for (int b = 0; b < 4; ++b) acc[a][b] = (f32x4){0.f, 0.f, 0.f, 0.f};

  for (int kt = 0; kt < 8; ++kt) {
    const int k0 = kt * 64;
    __syncthreads();
#pragma unroll
    for (int i = 0; i < 4; ++i) {
      int row = wid * 32 + i * 8 + l8;
      GLOAD16(xb  + (size_t)(m0 + row) * 512 + k0 + colel, At + wid * 4096 + i * 1024);
      GLOAD16(wqT + (size_t)(n0 + row) * 512 + k0 + colel, Bt + wid * 4096 + i * 1024);
    }
    __syncthreads();
#pragma unroll
    for (int kk = 0; kk < 2; ++kk) {
      bf16x8 af[4], bf[4];
      const int kb = (kk * 32 + 8 * g) * 2;
#pragma unroll
      for (int mi = 0; mi < 4; ++mi)
        af[mi] = *reinterpret_cast<const bf16x8*>(At + swz(wm * 64 + mi * 16 + r, kb));
#pragma unroll
      for (int ni = 0; ni < 4; ++ni)
        bf[ni] = *reinterpret_cast<const bf16x8*>(Bt + swz(wn * 64 + ni * 16 + r, kb));
#pragma unroll
      for (int mi = 0; mi < 4; ++mi)
#pragma unroll
        for (int ni = 0; ni < 4; ++ni)
          acc[mi][ni] = MFMA16(af[mi], bf[ni], acc[mi][ni]);
    }
  }
  const int s = n0 >> 9;  // 0=q 1=k 2=val
#pragma unroll
  for (int mi = 0; mi < 4; ++mi)
#pragma unroll
    for (int ni = 0; ni < 4; ++ni)
#pragma unroll
      for (int i = 0; i < 4; ++i) {
        int m = m0 + wm * 64 + mi * 16 + 4 * g + i;   // D row = 4g+i (m89)
        int n = n0 + wn * 64 + ni * 16 + r;           // D col = lane&15
        int b = m >> 10, v = m & 1023;
        int cc = n & 511, h = cc >> 6, d = cc & 63;
        int bh = b * 8 + h;
        unsigned short bfv = f2bf(acc[mi][ni][i]);
        if (s == 2)      valT[((size_t)bh * 64 + d) * 1024 + v] = bfv;
        else if (s == 0) q [((size_t)bh * 1024 + v) * 64 + d] = bfv;
        else             k_[((size_t)bh * 1024 + v) * 64 + d] = bfv;
      }
}

// ------- attention: fused normalize + direct f32 attn store (plain) --------
// One block = (b,h, 16 q-rows). Wave w owns score cols [256w, 256w+256).
// attn written straight from registers in the normalize loop: 4x64B covered
// segments per store; adjacent ct fills the other half of each 128B line ->
// L2 merges (plain stores, no nt). P (bf16) kept only as the PV A-operand.
#define PSTR 1032
__global__ __launch_bounds__(256, 4) void k_attn(
    const unsigned short* __restrict__ q, const unsigned short* __restrict__ k_,
    const unsigned short* __restrict__ valT,
    const unsigned short* __restrict__ biasT,
    float* __restrict__ attn, unsigned short* __restrict__ oh)
{
  __shared__ unsigned short P[16 * PSTR];   // bf16, 33 KB
  __shared__ float red[2][4][16];
  const int tid = threadIdx.x;
  const int wid = tid >> 6, lane = tid & 63, g = lane >> 4, r = lane & 15;
  // bijective XCD swizzle (4096 % 8 == 0): XCD j gets work ids [512j, 512j+512)
  const int blk = ((blockIdx.x & 7) << 9) | (blockIdx.x >> 3);
  const int h  = blk >> 9;                  // outermost: one head per XCD
  const int vt = (blk >> 3) & 63;
  const int b  = blk & 7;                   // innermost: bias-tile sharers adjacent
  const int bh = b * 8 + h;
  const int v0 = vt * 16;

  // stage bias tile [16 rows][1024 w] bf16 into P (uint4 = 8 elems, coalesced)
  const unsigned short* bb = biasT + ((size_t)h << 20) + (size_t)v0 * 1024;
#pragma unroll
  for (int it = 0; it < 8; ++it) {
    int e = tid + it * 256;                  // 0..2047: row=e>>7, chunk=e&127
    int row = e >> 7, c8 = e & 127;
    *reinterpret_cast<uint4*>(&P[row * PSTR + c8 * 8]) =
        *reinterpret_cast<const uint4*>(bb + (size_t)row * 1024 + c8 * 8);
  }

  // Q fragments in registers (A-operand: row=r, k-slice 8g)
  const unsigned short* qp = q + ((size_t)bh * 1024 + v0) * 64;
  bf16x8 qf[2];
#pragma unroll
  for (int kk = 0; kk < 2; ++kk)
    qf[kk] = *reinterpret_cast<const bf16x8*>(qp + r * 64 + kk * 32 + 8 * g);
  __syncthreads();

  // QK: scores in registers; bias from LDS
  const unsigned short* kb = k_ + (size_t)bh * 65536;
  f32x4 s[16];
#pragma unroll
  for (int ct = 0; ct < 16; ++ct) {
    const int wcol = wid * 256 + ct * 16 + r;
    f32x4 acc = (f32x4){0.f, 0.f, 0.f, 0.f};
#pragma unroll
    for (int kk = 0; kk < 2; ++kk) {
      bf16x8 kf = *reinterpret_cast<const bf16x8*>(kb + (size_t)wcol * 64 + kk * 32 + 8 * g);
      acc = MFMA16(qf[kk], kf, acc);
    }
#pragma unroll
    for (int i = 0; i < 4; ++i)
      s[ct][i] = (acc[i] + bf2f(P[(4 * g + i) * PSTR + wcol])) * 0.125f;
  }

  // per-row max: local over ct, then shfl over the 16-lane r-group
  float mx[4] = {-1e30f, -1e30f, -1e30f, -1e30f};
#pragma unroll
  for (int ct = 0; ct < 16; ++ct)
#pragma unroll
    for (int i = 0; i < 4; ++i) mx[i] = fmaxf(mx[i], s[ct][i]);
#pragma unroll
  for (int o = 1; o <= 8; o <<= 1)
#pragma unroll
    for (int i = 0; i < 4; ++i) mx[i] = fmaxf(mx[i], __shfl_xor(mx[i], o, 64));
  if (r == 0)
#pragma unroll
    for (int i = 0; i < 4; ++i) red[0][wid][4 * g + i] = mx[i];
  __syncthreads();
#pragma unroll
  for (int i = 0; i < 4; ++i) {
    float M = red[0][0][4 * g + i];
#pragma unroll
    for (int w = 1; w < 4; ++w) M = fmaxf(M, red[0][w][4 * g + i]);
    mx[i] = M;
  }

  // exp + per-row sum
  float sm[4] = {0.f, 0.f, 0.f, 0.f};
#pragma unroll
  for (int ct = 0; ct < 16; ++ct)
#pragma unroll
    for (int i = 0; i < 4; ++i) {
      float e = __expf(s[ct][i] - mx[i]);
      s[ct][i] = e;
      sm[i] += e;
    }
#pragma unroll
  for (int o = 1; o <= 8; o <<= 1)
#pragma unroll
    for (int i = 0; i < 4; ++i) sm[i] += __shfl_xor(sm[i], o, 64);
  if (r == 0)
#pragma unroll
    for (int i = 0; i < 4; ++i) red[1][wid][4 * g + i] = sm[i];
  __syncthreads();                 // all QK bias reads done before P overwrite
  float inv[4];
#pragma unroll
  for (int i = 0; i < 4; ++i) {
    float T = red[1][0][4 * g + i] + red[1][1][4 * g + i] +
              red[1][2][4 * g + i] + red[1][3][4 * g + i];
    inv[i] = 1.0f / T;
  }

  // fused: normalize -> plain f32 attn store + bf16 P (PV operand)
  float* ab = attn + ((size_t)bh * 1024 + v0) * 1024;
#pragma unroll
  for (int ct = 0; ct < 16; ++ct) {
    const int col = wid * 256 + ct * 16 + r;
#pragma unroll
    for (int i = 0; i < 4; ++i) {
      const int row = 4 * g + i;
      float a = s[ct][i] * inv[i];
      ab[(size_t)row * 1024 + col] = a;      // plain store; L2 merges halves
      P[row * PSTR + col] = f2bf(a);
    }
  }
  __syncthreads();

  // PV: out(16x64) = P(16x1024) @ val(1024x64); wave owns 16 out cols.
  const unsigned short* vT = valT + ((size_t)bh * 64 + wid * 16) * 1024;
  f32x4 a0 = (f32x4){0.f,0.f,0.f,0.f}, a1 = a0;
  for (int kc = 0; kc < 32; kc += 2) {
    const int base = r * PSTR, vbase = kc * 32 + 8 * g;
    bf16x8 p0 = *reinterpret_cast<const bf16x8*>(&P[base + vbase]);
    bf16x8 p1 = *reinterpret_cast<const bf16x8*>(&P[base + vbase + 32]);
    bf16x8 v0_ = *reinterpret_cast<const bf16x8*>(vT + (size_t)r * 1024 + vbase);
    bf16x8 v1_ = *reinterpret_cast<const bf16x8*>(vT + (size_t)r * 1024 + vbase + 32);
    a0 = MFMA16(p0, v0_, a0);
    a1 = MFMA16(p1, v1_, a1);
  }
  f32x4 acc = a0 + a1;
#pragma unroll
  for (int i = 0; i < 4; ++i) {
    size_t oi = ((size_t)(b * 1024 + v0 + 4 * g + i)) * 512 + h * 64 + wid * 16 + r;
    oh[oi] = f2bf(acc[i]);
  }
}

// ------- output GEMM: out = oh @ w_out + b_out, async staging --------------
__global__ __launch_bounds__(256) void k_out(
    const unsigned short* __restrict__ oh, const unsigned short* __restrict__ woT,
    const float* __restrict__ b_out, float* __restrict__ out)
{
  __shared__ char lds[32768];
  char* At = lds; char* Bt = lds + 16384;
  const int tid = threadIdx.x;
  const int wid = tid >> 6, lane = tid & 63, g = lane >> 4, r = lane & 15;
  const int wm = wid >> 1, wn = wid & 1;
  const int m0 = blockIdx.x * 128, n0 = blockIdx.y * 128;
  const int l8 = lane >> 3;
  const int colel = ((lane & 7) ^ l8) * 8;   // pre-swizzled source column (elems)

  f32x4 acc[4][4];
#pragma unroll
  for (int a = 0; a < 4; ++a)
#pragma unroll
    for (int b = 0; b < 4; ++b) acc[a][b] = (f32x4){0.f, 0.f, 0.f, 0.f};

  for (int kt = 0; kt < 8; ++kt) {
    const int k0 = kt * 64;
    __syncthreads();
#pragma unroll
    for (int i = 0; i < 4; ++i) {
      int row = wid * 32 + i * 8 + l8;
      GLOAD16(oh  + (size_t)(m0 + row) * 512 + k0 + colel, At + wid * 4096 + i * 1024);
      GLOAD16(woT + (size_t)(n0 + row) * 512 + k0 + colel, Bt + wid * 4096 + i * 1024);
    }
    __syncthreads();
#pragma unroll
    for (int kk = 0; kk < 2; ++kk) {
      bf16x8 a4[4], b4[4];
      const int kb = (kk * 32 + 8 * g) * 2;
#pragma unroll
      for (int mi = 0; mi < 4; ++mi)
        a4[mi] = *reinterpret_cast<const bf16x8*>(At + swz(wm * 64 + mi * 16 + r, kb));
#pragma unroll
      for (int ni = 0; ni < 4; ++ni)
        b4[ni] = *reinterpret_cast<const bf16x8*>(Bt + swz(wn * 64 + ni * 16 + r, kb));
#pragma unroll
      for (int mi = 0; mi < 4; ++mi)
#pragma unroll
        for (int ni = 0; ni < 4; ++ni)
          acc[mi][ni] = MFMA16(a4[mi], b4[ni], acc[mi][ni]);
    }
  }
#pragma unroll
  for (int mi = 0; mi < 4; ++mi)
#pragma unroll
    for (int ni = 0; ni < 4; ++ni)
#pragma unroll
      for (int i = 0; i < 4; ++i) {
        int m = m0 + wm * 64 + mi * 16 + 4 * g + i;
        int n = n0 + wn * 64 + ni * 16 + r;
        float v = acc[mi][ni][i] + b_out[n];
        __builtin_nontemporal_store(v, out + (size_t)m * 512 + n);
      }
}

extern "C" void kernel_launch(void* const* d_in, const int* in_sizes, int n_in,
                              void* d_out, int out_size, void* d_ws, size_t ws_size,
                              hipStream_t stream) {
  // Bind inputs BY SIZE (all six element counts distinct) — immune to order.
  const float *x = nullptr, *w_qkv = nullptr, *w_out = nullptr,
              *b_out = nullptr, *rpe = nullptr;
  const int* hop = nullptr;
  for (int i = 0; i < n_in; ++i) {
    switch (in_sizes[i]) {
      case 4194304: x     = (const float*)d_in[i]; break;  // (8,1024,512)
      case 786432:  w_qkv = (const float*)d_in[i]; break;  // (512,1536)
      case 262144:  w_out = (const float*)d_in[i]; break;  // (512,512)
      case 512:     b_out = (const float*)d_in[i]; break;  // (512,)
      case 72:      rpe   = (const float*)d_in[i]; break;  // (8,9)
      case 1048576: hop   = (const int*)d_in[i];   break;  // (1024,1024) int32
    }
  }

  float* out  = (float*)d_out;                 // f32 outputs
  float* attn = out + (size_t)4194304;         // attn section (8,8,1024,1024)

  char* ws = (char*)d_ws;
  unsigned short* q_    = (unsigned short*)(ws);                   // 8 MB
  unsigned short* k_    = (unsigned short*)(ws + (size_t) 8388608);// 8 MB
  unsigned short* valT  = (unsigned short*)(ws + (size_t)16777216);// 8 MB
  unsigned short* oh    = (unsigned short*)(ws + (size_t)25165824);// 8 MB
  unsigned short* wqT   = (unsigned short*)(ws + (size_t)33554432);// 1.5 MB
  unsigned short* woT   = (unsigned short*)(ws + (size_t)35127296);// 0.5 MB
  unsigned short* biasT = (unsigned short*)(ws + (size_t)35651584);// 16 MB
  unsigned short* xb    = (unsigned short*)(ws + (size_t)52428800);// 8 MB
  // total ~60 MB of d_ws

  // prep grid: 256 transpose tiles + 1024 xb blocks + 4096 bias blocks
  k_prep<<<dim3(5376), dim3(256), 0, stream>>>(w_qkv, w_out, x, hop, rpe,
                                               wqT, woT, xb, biasT);
  k_qkv<<<dim3(64, 12), dim3(256), 0, stream>>>(xb, wqT, q_, k_, valT);
  k_attn<<<dim3(4096), dim3(256), 0, stream>>>(q_, k_, valT, biasT, attn, oh);
  k_out<<<dim3(64, 4), dim3(256), 0, stream>>>(oh, woT, b_out, out);
}

// Round 22
// 194.054 us; speedup vs baseline: 1.0922x; 1.0759x over previous
//
#include <hip/hip_runtime.h>

typedef __attribute__((ext_vector_type(8))) short bf16x8;
typedef __attribute__((ext_vector_type(4))) float f32x4;

#define MFMA16(A,B,C) __builtin_amdgcn_mfma_f32_16x16x32_bf16(A,B,C,0,0,0)

typedef const __attribute__((address_space(1))) void gas_t;
typedef __attribute__((address_space(3))) void las_t;
#define GLOAD16(g, l) __builtin_amdgcn_global_load_lds((gas_t*)(g), (las_t*)(l), 16, 0, 0)

__device__ __forceinline__ unsigned short f2bf(float f){
  unsigned int u = __float_as_uint(f);
  u += 0x7FFFu + ((u >> 16) & 1u);        // round-to-nearest-even
  return (unsigned short)(u >> 16);
}
__device__ __forceinline__ float bf2f(unsigned short s){
  return __uint_as_float(((unsigned int)s) << 16);
}
// byte offset into a [rows][64] bf16 LDS tile (128B rows), XOR-swizzled (G4)
__device__ __forceinline__ int swz(int row, int kbyte){
  return (row * 128 + kbyte) ^ ((row & 7) << 4);
}

// -- prep (merged, tiled-transpose): blocks 0-255 transpose wqT/woT via LDS
//    (64x64 f32 tile, [64][65] padding); 256-1279 xb convert; 1280+ bias.
__global__ __launch_bounds__(256) void k_prep(
    const float* __restrict__ w_qkv, const float* __restrict__ w_out,
    const float* __restrict__ x,
    const int* __restrict__ hop, const float* __restrict__ rpe_bias,
    unsigned short* __restrict__ wqT, unsigned short* __restrict__ woT,
    unsigned short* __restrict__ xb, unsigned short* __restrict__ biasT)
{
  __shared__ float tile[64][65];
  __shared__ float rl[72];
  const int bid = blockIdx.x, tid = threadIdx.x;
  if (bid < 256) {
    // tiled transpose: coalesced reads along n, coalesced writes along kq
    const float* src; unsigned short* dst; int srcld, kq0, n0;
    if (bid < 192) {                       // wqT: 24 n-tiles x 8 kq-tiles
      int tn = bid >> 3, tk = bid & 7;
      src = w_qkv; dst = wqT; srcld = 1536; kq0 = tk * 64; n0 = tn * 64;
    } else {                               // woT: 8 x 8 tiles
      int j = bid - 192; int tn = j >> 3, tk = j & 7;
      src = w_out; dst = woT; srcld = 512; kq0 = tk * 64; n0 = tn * 64;
    }
    const int c = tid & 63, r4 = tid >> 6;
#pragma unroll
    for (int i = 0; i < 16; ++i) {
      int rr = r4 * 16 + i;
      tile[rr][c] = src[(size_t)(kq0 + rr) * srcld + n0 + c];
    }
    __syncthreads();
#pragma unroll
    for (int i = 0; i < 16; ++i) {
      int rr = r4 * 16 + i;                // output row = n index
      dst[(size_t)(n0 + rr) * 512 + kq0 + c] = f2bf(tile[c][rr]);
    }
  } else if (bid < 1280) {                 // xb: 1024 blocks x 1024 quads
    int base = (bid - 256) * 1024 + tid;
#pragma unroll
    for (int i = 0; i < 4; ++i) {
      int j = base + i * 256;
      float4 xv = *reinterpret_cast<const float4*>(x + (size_t)j * 4);
      ushort4 o;
      o.x = f2bf(xv.x); o.y = f2bf(xv.y); o.z = f2bf(xv.z); o.w = f2bf(xv.w);
      *reinterpret_cast<ushort4*>(xb + (size_t)j * 4) = o;
    }
  } else {                                 // bias: 4096 blocks, coalesced
    if (tid < 72) rl[tid] = rpe_bias[tid];
    __syncthreads();
    int j = (bid - 1280) * 256 + tid;
    int hv = hop[j];
#pragma unroll
    for (int h = 0; h < 8; ++h)
      biasT[((size_t)h << 20) + j] = f2bf(rl[h * 9 + hv]);
  }
}

// ------- QKV GEMM: qkv = xb @ w_qkv, async global_load_lds staging ---------
__global__ __launch_bounds__(256) void k_qkv(
    const unsigned short* __restrict__ xb, const unsigned short* __restrict__ wqT,
    unsigned short* __restrict__ q, unsigned short* __restrict__ k_,
    unsigned short* __restrict__ valT)
{
  __shared__ char lds[32768];
  char* At = lds; char* Bt = lds + 16384;
  const int tid = threadIdx.x;
  const int wid = tid >> 6, lane = tid & 63, g = lane >> 4, r = lane & 15;
  const int wm = wid >> 1, wn = wid & 1;
  const int m0 = blockIdx.x * 128, n0 = blockIdx.y * 128;
  const int l8 = lane >> 3;
  const int colel = ((lane & 7) ^ l8) * 8;   // pre-swizzled source column (elems)

  f32x4 acc[4][4];
#pragma unroll
  for (int a = 0; a < 4; ++a)
#pragma unroll
    for (int b = 0; b < 4; ++b) acc[a][b] = (f32x4){0.f, 0.f, 0.f, 0.f};

  for (int kt = 0; kt < 8; ++kt) {
    const int k0 = kt * 64;
    __syncthreads();
#pragma unroll
    for (int i = 0; i < 4; ++i) {
      int row = wid * 32 + i * 8 + l8;
      GLOAD16(xb  + (size_t)(m0 + row) * 512 + k0 + colel, At + wid * 4096 + i * 1024);
      GLOAD16(wqT + (size_t)(n0 + row) * 512 + k0 + colel, Bt + wid * 4096 + i * 1024);
    }
    __syncthreads();
#pragma unroll
    for (int kk = 0; kk < 2; ++kk) {
      bf16x8 af[4], bf[4];
      const int kb = (kk * 32 + 8 * g) * 2;
#pragma unroll
      for (int mi = 0; mi < 4; ++mi)
        af[mi] = *reinterpret_cast<const bf16x8*>(At + swz(wm * 64 + mi * 16 + r, kb));
#pragma unroll
      for (int ni = 0; ni < 4; ++ni)
        bf[ni] = *reinterpret_cast<const bf16x8*>(Bt + swz(wn * 64 + ni * 16 + r, kb));
#pragma unroll
      for (int mi = 0; mi < 4; ++mi)
#pragma unroll
        for (int ni = 0; ni < 4; ++ni)
          acc[mi][ni] = MFMA16(af[mi], bf[ni], acc[mi][ni]);
    }
  }
  const int s = n0 >> 9;  // 0=q 1=k 2=val
#pragma unroll
  for (int mi = 0; mi < 4; ++mi)
#pragma unroll
    for (int ni = 0; ni < 4; ++ni)
#pragma unroll
      for (int i = 0; i < 4; ++i) {
        int m = m0 + wm * 64 + mi * 16 + 4 * g + i;   // D row = 4g+i (m89)
        int n = n0 + wn * 64 + ni * 16 + r;           // D col = lane&15
        int b = m >> 10, v = m & 1023;
        int cc = n & 511, h = cc >> 6, d = cc & 63;
        int bh = b * 8 + h;
        unsigned short bfv = f2bf(acc[mi][ni][i]);
        if (s == 2)      valT[((size_t)bh * 64 + d) * 1024 + v] = bfv;
        else if (s == 0) q [((size_t)bh * 1024 + v) * 64 + d] = bfv;
        else             k_[((size_t)bh * 1024 + v) * 64 + d] = bfv;
      }
}

// ---------------- attention (r19 best config): regs-scores + shfl softmax --
// One block = (b,h, 16 q-rows). Wave w owns score cols [256w, 256w+256).
// Work order (h, vt, b) with b INNERMOST; XCD j owns head h=j.
// Separate coalesced nt attn write from P (load-bearing: r21 showed fused
// plain stores cost +15us; r17 showed removing nt costs +6us).
#define PSTR 1032
__global__ __launch_bounds__(256, 4) void k_attn(
    const unsigned short* __restrict__ q, const unsigned short* __restrict__ k_,
    const unsigned short* __restrict__ valT,
    const unsigned short* __restrict__ biasT,
    float* __restrict__ attn, unsigned short* __restrict__ oh)
{
  __shared__ unsigned short P[16 * PSTR];   // bf16, 33 KB
  __shared__ float red[2][4][16];
  const int tid = threadIdx.x;
  const int wid = tid >> 6, lane = tid & 63, g = lane >> 4, r = lane & 15;
  // bijective XCD swizzle (4096 % 8 == 0): XCD j gets work ids [512j, 512j+512)
  const int blk = ((blockIdx.x & 7) << 9) | (blockIdx.x >> 3);
  const int h  = blk >> 9;                  // outermost: one head per XCD
  const int vt = (blk >> 3) & 63;
  const int b  = blk & 7;                   // innermost: bias-tile sharers adjacent
  const int bh = b * 8 + h;
  const int v0 = vt * 16;

  // stage bias tile [16 rows][1024 w] bf16 into P (uint4 = 8 elems, coalesced)
  const unsigned short* bb = biasT + ((size_t)h << 20) + (size_t)v0 * 1024;
#pragma unroll
  for (int it = 0; it < 8; ++it) {
    int e = tid + it * 256;                  // 0..2047: row=e>>7, chunk=e&127
    int row = e >> 7, c8 = e & 127;
    *reinterpret_cast<uint4*>(&P[row * PSTR + c8 * 8]) =
        *reinterpret_cast<const uint4*>(bb + (size_t)row * 1024 + c8 * 8);
  }

  // Q fragments in registers (A-operand: row=r, k-slice 8g)
  const unsigned short* qp = q + ((size_t)bh * 1024 + v0) * 64;
  bf16x8 qf[2];
#pragma unroll
  for (int kk = 0; kk < 2; ++kk)
    qf[kk] = *reinterpret_cast<const bf16x8*>(qp + r * 64 + kk * 32 + 8 * g);
  __syncthreads();

  // QK: scores in registers; bias from LDS
  const unsigned short* kb = k_ + (size_t)bh * 65536;
  f32x4 s[16];
#pragma unroll
  for (int ct = 0; ct < 16; ++ct) {
    const int wcol = wid * 256 + ct * 16 + r;
    f32x4 acc = (f32x4){0.f, 0.f, 0.f, 0.f};
#pragma unroll
    for (int kk = 0; kk < 2; ++kk) {
      bf16x8 kf = *reinterpret_cast<const bf16x8*>(kb + (size_t)wcol * 64 + kk * 32 + 8 * g);
      acc = MFMA16(qf[kk], kf, acc);
    }
#pragma unroll
    for (int i = 0; i < 4; ++i)
      s[ct][i] = (acc[i] + bf2f(P[(4 * g + i) * PSTR + wcol])) * 0.125f;
  }

  // per-row max: local over ct, then shfl over the 16-lane r-group
  float mx[4] = {-1e30f, -1e30f, -1e30f, -1e30f};
#pragma unroll
  for (int ct = 0; ct < 16; ++ct)
#pragma unroll
    for (int i = 0; i < 4; ++i) mx[i] = fmaxf(mx[i], s[ct][i]);
#pragma unroll
  for (int o = 1; o <= 8; o <<= 1)
#pragma unroll
    for (int i = 0; i < 4; ++i) mx[i] = fmaxf(mx[i], __shfl_xor(mx[i], o, 64));
  if (r == 0)
#pragma unroll
    for (int i = 0; i < 4; ++i) red[0][wid][4 * g + i] = mx[i];
  __syncthreads();
#pragma unroll
  for (int i = 0; i < 4; ++i) {
    float M = red[0][0][4 * g + i];
#pragma unroll
    for (int w = 1; w < 4; ++w) M = fmaxf(M, red[0][w][4 * g + i]);
    mx[i] = M;
  }

  // exp + per-row sum
  float sm[4] = {0.f, 0.f, 0.f, 0.f};
#pragma unroll
  for (int ct = 0; ct < 16; ++ct)
#pragma unroll
    for (int i = 0; i < 4; ++i) {
      float e = __expf(s[ct][i] - mx[i]);
      s[ct][i] = e;
      sm[i] += e;
    }
#pragma unroll
  for (int o = 1; o <= 8; o <<= 1)
#pragma unroll
    for (int i = 0; i < 4; ++i) sm[i] += __shfl_xor(sm[i], o, 64);
  if (r == 0)
#pragma unroll
    for (int i = 0; i < 4; ++i) red[1][wid][4 * g + i] = sm[i];
  __syncthreads();                 // all QK bias reads done before P overwrite
  float inv[4];
#pragma unroll
  for (int i = 0; i < 4; ++i) {
    float T = red[1][0][4 * g + i] + red[1][1][4 * g + i] +
              red[1][2][4 * g + i] + red[1][3][4 * g + i];
    inv[i] = 1.0f / T;
  }

  // normalize into bf16 P only (no scattered global writes)
#pragma unroll
  for (int ct = 0; ct < 16; ++ct) {
    const int col = wid * 256 + ct * 16 + r;
#pragma unroll
    for (int i = 0; i < 4; ++i)
      P[(4 * g + i) * PSTR + col] = f2bf(s[ct][i] * inv[i]);
  }
  __syncthreads();

  // coalesced attn write from P: lane -> f32x4 (16B) nontemporal, 1KB/wave.
  float* ab = attn + ((size_t)bh * 1024 + v0) * 1024;
#pragma unroll
  for (int it = 0; it < 16; ++it) {
    int e = tid + it * 256;                 // 0..4095: row=e>>8, quad=e&255
    int row = e >> 8, q4 = e & 255;
    uint2 pv = *reinterpret_cast<const uint2*>(&P[row * PSTR + q4 * 4]);
    f32x4 o;
    o[0] = bf2f((unsigned short)(pv.x      ));
    o[1] = bf2f((unsigned short)(pv.x >> 16));
    o[2] = bf2f((unsigned short)(pv.y      ));
    o[3] = bf2f((unsigned short)(pv.y >> 16));
    __builtin_nontemporal_store(o, reinterpret_cast<f32x4*>(ab + (size_t)row * 1024 + q4 * 4));
  }

  // PV: out(16x64) = P(16x1024) @ val(1024x64); wave owns 16 out cols.
  const unsigned short* vT = valT + ((size_t)bh * 64 + wid * 16) * 1024;
  f32x4 a0 = (f32x4){0.f,0.f,0.f,0.f}, a1 = a0;
  for (int kc = 0; kc < 32; kc += 2) {
    const int base = r * PSTR, vbase = kc * 32 + 8 * g;
    bf16x8 p0 = *reinterpret_cast<const bf16x8*>(&P[base + vbase]);
    bf16x8 p1 = *reinterpret_cast<const bf16x8*>(&P[base + vbase + 32]);
    bf16x8 v0_ = *reinterpret_cast<const bf16x8*>(vT + (size_t)r * 1024 + vbase);
    bf16x8 v1_ = *reinterpret_cast<const bf16x8*>(vT + (size_t)r * 1024 + vbase + 32);
    a0 = MFMA16(p0, v0_, a0);
    a1 = MFMA16(p1, v1_, a1);
  }
  f32x4 acc = a0 + a1;
#pragma unroll
  for (int i = 0; i < 4; ++i) {
    size_t oi = ((size_t)(b * 1024 + v0 + 4 * g + i)) * 512 + h * 64 + wid * 16 + r;
    oh[oi] = f2bf(acc[i]);
  }
}

// ------- output GEMM: out = oh @ w_out + b_out, async staging --------------
__global__ __launch_bounds__(256) void k_out(
    const unsigned short* __restrict__ oh, const unsigned short* __restrict__ woT,
    const float* __restrict__ b_out, float* __restrict__ out)
{
  __shared__ char lds[32768];
  char* At = lds; char* Bt = lds + 16384;
  const int tid = threadIdx.x;
  const int wid = tid >> 6, lane = tid & 63, g = lane >> 4, r = lane & 15;
  const int wm = wid >> 1, wn = wid & 1;
  const int m0 = blockIdx.x * 128, n0 = blockIdx.y * 128;
  const int l8 = lane >> 3;
  const int colel = ((lane & 7) ^ l8) * 8;   // pre-swizzled source column (elems)

  f32x4 acc[4][4];
#pragma unroll
  for (int a = 0; a < 4; ++a)
#pragma unroll
    for (int b = 0; b < 4; ++b) acc[a][b] = (f32x4){0.f, 0.f, 0.f, 0.f};

  for (int kt = 0; kt < 8; ++kt) {
    const int k0 = kt * 64;
    __syncthreads();
#pragma unroll
    for (int i = 0; i < 4; ++i) {
      int row = wid * 32 + i * 8 + l8;
      GLOAD16(oh  + (size_t)(m0 + row) * 512 + k0 + colel, At + wid * 4096 + i * 1024);
      GLOAD16(woT + (size_t)(n0 + row) * 512 + k0 + colel, Bt + wid * 4096 + i * 1024);
    }
    __syncthreads();
#pragma unroll
    for (int kk = 0; kk < 2; ++kk) {
      bf16x8 a4[4], b4[4];
      const int kb = (kk * 32 + 8 * g) * 2;
#pragma unroll
      for (int mi = 0; mi < 4; ++mi)
        a4[mi] = *reinterpret_cast<const bf16x8*>(At + swz(wm * 64 + mi * 16 + r, kb));
#pragma unroll
      for (int ni = 0; ni < 4; ++ni)
        b4[ni] = *reinterpret_cast<const bf16x8*>(Bt + swz(wn * 64 + ni * 16 + r, kb));
#pragma unroll
      for (int mi = 0; mi < 4; ++mi)
#pragma unroll
        for (int ni = 0; ni < 4; ++ni)
          acc[mi][ni] = MFMA16(a4[mi], b4[ni], acc[mi][ni]);
    }
  }
#pragma unroll
  for (int mi = 0; mi < 4; ++mi)
#pragma unroll
    for (int ni = 0; ni < 4; ++ni)
#pragma unroll
      for (int i = 0; i < 4; ++i) {
        int m = m0 + wm * 64 + mi * 16 + 4 * g + i;
        int n = n0 + wn * 64 + ni * 16 + r;
        float v = acc[mi][ni][i] + b_out[n];
        __builtin_nontemporal_store(v, out + (size_t)m * 512 + n);
      }
}

extern "C" void kernel_launch(void* const* d_in, const int* in_sizes, int n_in,
                              void* d_out, int out_size, void* d_ws, size_t ws_size,
                              hipStream_t stream) {
  // Bind inputs BY SIZE (all six element counts distinct) — immune to order.
  const float *x = nullptr, *w_qkv = nullptr, *w_out = nullptr,
              *b_out = nullptr, *rpe = nullptr;
  const int* hop = nullptr;
  for (int i = 0; i < n_in; ++i) {
    switch (in_sizes[i]) {
      case 4194304: x     = (const float*)d_in[i]; break;  // (8,1024,512)
      case 786432:  w_qkv = (const float*)d_in[i]; break;  // (512,1536)
      case 262144:  w_out = (const float*)d_in[i]; break;  // (512,512)
      case 512:     b_out = (const float*)d_in[i]; break;  // (512,)
      case 72:      rpe   = (const float*)d_in[i]; break;  // (8,9)
      case 1048576: hop   = (const int*)d_in[i];   break;  // (1024,1024) int32
    }
  }

  float* out  = (float*)d_out;                 // f32 outputs
  float* attn = out + (size_t)4194304;         // attn section (8,8,1024,1024)

  char* ws = (char*)d_ws;
  unsigned short* q_    = (unsigned short*)(ws);                   // 8 MB
  unsigned short* k_    = (unsigned short*)(ws + (size_t) 8388608);// 8 MB
  unsigned short* valT  = (unsigned short*)(ws + (size_t)16777216);// 8 MB
  unsigned short* oh    = (unsigned short*)(ws + (size_t)25165824);// 8 MB
  unsigned short* wqT   = (unsigned short*)(ws + (size_t)33554432);// 1.5 MB
  unsigned short* woT   = (unsigned short*)(ws + (size_t)35127296);// 0.5 MB
  unsigned short* biasT = (unsigned short*)(ws + (size_t)35651584);// 16 MB
  unsigned short* xb    = (unsigned short*)(ws + (size_t)52428800);// 8 MB
  // total ~60 MB of d_ws

  // prep grid: 256 transpose tiles + 1024 xb blocks + 4096 bias blocks
  k_prep<<<dim3(5376), dim3(256), 0, stream>>>(w_qkv, w_out, x, hop, rpe,
                                               wqT, woT, xb, biasT);
  k_qkv<<<dim3(64, 12), dim3(256), 0, stream>>>(xb, wqT, q_, k_, valT);
  k_attn<<<dim3(4096), dim3(256), 0, stream>>>(q_, k_, valT, biasT, attn, oh);
  k_out<<<dim3(64, 4), dim3(256), 0, stream>>>(oh, woT, b_out, out);
}